// Round 4
// baseline (251.967 us; speedup 1.0000x reference)
//
#include <hip/hip_runtime.h>
#include <hip/hip_bf16.h>
#include <stdint.h>

// LSTM cell: B=4096, IN=1024, H=1024.
// gates = [x|h] @ [Wx|Wh]^T  -> M=4096, K=2048, N=4 gates x 1024 units
// Strategy: pack fp32->bf16 (A and stacked W) into ws, then one MFMA GEMM
// (m97-style 128-row tile, BK=64, global_load_lds w=16) whose N-tile is
// 32 units x 4 gates so the LSTM epilogue is per-lane register-local.

#define BDIM 4096
#define HDIM 1024
#define KDIM 2048
#define BK   64
#define NT   (KDIM / BK)   // 32 K-steps

typedef __attribute__((ext_vector_type(8))) short bf16x8;
typedef __attribute__((ext_vector_type(4))) float f32x4;
typedef __attribute__((ext_vector_type(8))) unsigned short u16x8;

__device__ __forceinline__ unsigned short f2bf(float f) {
  union { float f; uint32_t u; } v; v.f = f;
  uint32_t u = v.u;
  u += 0x7FFFu + ((u >> 16) & 1);   // round-to-nearest-even
  return (unsigned short)(u >> 16);
}

// ---------------- pack kernels: fp32 -> bf16 ----------------

__global__ __launch_bounds__(256) void pack_A_kernel(const float* __restrict__ x,
                                                     const float* __restrict__ h,
                                                     unsigned short* __restrict__ Ap) {
  int t = blockIdx.x * 256 + threadIdx.x;   // 4096*2048/8 = 1,048,576 threads
  int b = t >> 8;                            // batch row
  int k = (t & 255) << 3;                    // col (multiple of 8)
  const float* src = (k < 1024) ? (x + (size_t)b * 1024 + k)
                                : (h + (size_t)b * 1024 + (k - 1024));
  float4 v0 = *(const float4*)src;
  float4 v1 = *(const float4*)(src + 4);
  u16x8 o;
  o[0] = f2bf(v0.x); o[1] = f2bf(v0.y); o[2] = f2bf(v0.z); o[3] = f2bf(v0.w);
  o[4] = f2bf(v1.x); o[5] = f2bf(v1.y); o[6] = f2bf(v1.z); o[7] = f2bf(v1.w);
  *(u16x8*)(Ap + (size_t)b * 2048 + k) = o;
}

__global__ __launch_bounds__(256) void pack_W_kernel(
    const float* __restrict__ W_ii, const float* __restrict__ W_if,
    const float* __restrict__ W_ig, const float* __restrict__ W_io,
    const float* __restrict__ W_hi, const float* __restrict__ W_hf,
    const float* __restrict__ W_hg, const float* __restrict__ W_ho,
    unsigned short* __restrict__ Wp) {
  int t = blockIdx.x * 256 + threadIdx.x;
  int r = t >> 8;            // 0..4095 packed row = g*1024 + u
  int k = (t & 255) << 3;
  int g = r >> 10;
  int u = r & 1023;
  const float* wx = (g == 0) ? W_ii : (g == 1) ? W_if : (g == 2) ? W_ig : W_io;
  const float* wh = (g == 0) ? W_hi : (g == 1) ? W_hf : (g == 2) ? W_hg : W_ho;
  const float* src = (k < 1024) ? (wx + (size_t)u * 1024 + k)
                                : (wh + (size_t)u * 1024 + (k - 1024));
  float4 v0 = *(const float4*)src;
  float4 v1 = *(const float4*)(src + 4);
  u16x8 o;
  o[0] = f2bf(v0.x); o[1] = f2bf(v0.y); o[2] = f2bf(v0.z); o[3] = f2bf(v0.w);
  o[4] = f2bf(v1.x); o[5] = f2bf(v1.y); o[6] = f2bf(v1.z); o[7] = f2bf(v1.w);
  *(u16x8*)(Wp + (size_t)r * 2048 + k) = o;
}

// ---------------- fused GEMM + LSTM epilogue ----------------

#define GLOAD_LDS16(g, l)                                                            \
  __builtin_amdgcn_global_load_lds(                                                  \
      (const __attribute__((address_space(1))) unsigned int*)(g),                    \
      (__attribute__((address_space(3))) unsigned int*)(l), 16, 0, 0)

__device__ __forceinline__ float fast_sigmoid(float x) {
  return 1.f / (1.f + __expf(-x));
}
__device__ __forceinline__ float fast_tanh(float x) {
  // stable: +/-inf exp saturates to +/-1
  return 1.f - 2.f / (1.f + __expf(2.f * x));
}

__global__ __launch_bounds__(256) void lstm_gemm_kernel(
    const unsigned short* __restrict__ Ap, const unsigned short* __restrict__ Wp,
    const float* __restrict__ b_ii, const float* __restrict__ b_hi,
    const float* __restrict__ b_if, const float* __restrict__ b_hf,
    const float* __restrict__ b_ig, const float* __restrict__ b_hg,
    const float* __restrict__ b_io, const float* __restrict__ b_ho,
    const float* __restrict__ prev_c,
    float* __restrict__ out_h, float* __restrict__ out_c) {
  __shared__ unsigned short As[128][64];   // 128 batch rows x BK
  __shared__ unsigned short Ws[128][64];   // 4 gates x 32 units x BK

  const int tid  = threadIdx.x;
  const int lane = tid & 63;
  const int wave = tid >> 6;       // 0..3
  const int mblk = blockIdx.x;     // 0..31 (batch/128)
  const int ublk = blockIdx.y;     // 0..31 (units/32)
  const int wm   = wave >> 1;      // 0..1: 64-row half
  const int wu   = wave & 1;       // 0..1: 16-unit half

  f32x4 acc[4][4];                 // [gate][m-frag]
#pragma unroll
  for (int g = 0; g < 4; ++g)
#pragma unroll
    for (int m = 0; m < 4; ++m) acc[g][m] = (f32x4){0.f, 0.f, 0.f, 0.f};

  // staging: each wave stages 32 rows of A and 32 rows of W (gate = wave)
  const int rsub = lane >> 3;         // 0..7 row within 8-row chunk
  const int csub = (lane & 7) << 3;   // 0..56 elem col (16B per lane)
  const unsigned short* ga0 = Ap + (size_t)(mblk * 128 + wave * 32 + rsub) * 2048 + csub;
  const unsigned short* gw0 = Wp + (size_t)(wave * 1024 + ublk * 32 + rsub) * 2048 + csub;

  for (int kt = 0; kt < NT; ++kt) {
    const unsigned short* ga = ga0 + kt * BK;
    const unsigned short* gw = gw0 + kt * BK;
#pragma unroll
    for (int j = 0; j < 4; ++j) {
      GLOAD_LDS16(ga + (size_t)j * 8 * 2048, &As[wave * 32 + j * 8][0]);
      GLOAD_LDS16(gw + (size_t)j * 8 * 2048, &Ws[wave * 32 + j * 8][0]);
    }
    __syncthreads();   // drains vmcnt: tiles resident

#pragma unroll
    for (int kk = 0; kk < 2; ++kk) {
      const int kb = kk * 32 + ((lane >> 4) << 3);
      bf16x8 af[4], bfr[4];
#pragma unroll
      for (int m = 0; m < 4; ++m)
        af[m] = *(const bf16x8*)&As[wm * 64 + m * 16 + (lane & 15)][kb];
#pragma unroll
      for (int g = 0; g < 4; ++g)
        bfr[g] = *(const bf16x8*)&Ws[g * 32 + wu * 16 + (lane & 15)][kb];
#pragma unroll
      for (int g = 0; g < 4; ++g)
#pragma unroll
        for (int m = 0; m < 4; ++m)
          acc[g][m] = __builtin_amdgcn_mfma_f32_16x16x32_bf16(af[m], bfr[g], acc[g][m], 0, 0, 0);
    }
    __syncthreads();   // reads done before next stage overwrites
  }

  // ---- epilogue: per-lane, all 4 gates local ----
  const int u = ublk * 32 + wu * 16 + (lane & 15);
  const float bs_i = b_ii[u] + b_hi[u];
  const float bs_f = b_if[u] + b_hf[u];
  const float bs_g = b_ig[u] + b_hg[u];
  const float bs_o = b_io[u] + b_ho[u];

#pragma unroll
  for (int m = 0; m < 4; ++m) {
    const int rbase = mblk * 128 + wm * 64 + m * 16 + ((lane >> 4) << 2);
#pragma unroll
    for (int r = 0; r < 4; ++r) {
      const int row = rbase + r;
      const float gi = fast_sigmoid(acc[0][m][r] + bs_i);
      const float gf = fast_sigmoid(acc[1][m][r] + bs_f);
      const float gg = fast_tanh   (acc[2][m][r] + bs_g);
      const float go = fast_sigmoid(acc[3][m][r] + bs_o);
      const float cp = prev_c[(size_t)row * 1024 + u];
      const float c  = gf * cp + gi * gg;
      const float hh = go * fast_tanh(c);
      out_h[(size_t)row * 1024 + u] = hh;
      out_c[(size_t)row * 1024 + u] = c;
    }
  }
}

// ---------------- launch ----------------

extern "C" void kernel_launch(void* const* d_in, const int* in_sizes, int n_in,
                              void* d_out, int out_size, void* d_ws, size_t ws_size,
                              hipStream_t stream) {
  const float* input_ = (const float*)d_in[0];
  const float* prev_h = (const float*)d_in[1];
  const float* prev_c = (const float*)d_in[2];
  const float* W_ii = (const float*)d_in[3];  const float* b_ii = (const float*)d_in[4];
  const float* W_hi = (const float*)d_in[5];  const float* b_hi = (const float*)d_in[6];
  const float* W_if = (const float*)d_in[7];  const float* b_if = (const float*)d_in[8];
  const float* W_hf = (const float*)d_in[9];  const float* b_hf = (const float*)d_in[10];
  const float* W_ig = (const float*)d_in[11]; const float* b_ig = (const float*)d_in[12];
  const float* W_hg = (const float*)d_in[13]; const float* b_hg = (const float*)d_in[14];
  const float* W_io = (const float*)d_in[15]; const float* b_io = (const float*)d_in[16];
  const float* W_ho = (const float*)d_in[17]; const float* b_ho = (const float*)d_in[18];

  unsigned short* Ap = (unsigned short*)d_ws;                   // 4096x2048 bf16 = 16MB
  unsigned short* Wp = Ap + (size_t)4096 * 2048;                // 4096x2048 bf16 = 16MB

  pack_A_kernel<<<4096, 256, 0, stream>>>(input_, prev_h, Ap);
  pack_W_kernel<<<4096, 256, 0, stream>>>(W_ii, W_if, W_ig, W_io,
                                          W_hi, W_hf, W_hg, W_ho, Wp);

  float* out_h = (float*)d_out;
  float* out_c = out_h + (size_t)4096 * 1024;
  dim3 grid(32, 32);   // x: batch/128, y: units/32
  lstm_gemm_kernel<<<grid, 256, 0, stream>>>(Ap, Wp,
                                             b_ii, b_hi, b_if, b_hf,
                                             b_ig, b_hg, b_io, b_ho,
                                             prev_c, out_h, out_c);
}

// Round 5
// 213.195 us; speedup vs baseline: 1.1819x; 1.1819x over previous
//
#include <hip/hip_runtime.h>
#include <hip/hip_bf16.h>
#include <stdint.h>

// LSTM cell: B=4096, IN=1024, H=1024.
// gates = [x|h] @ W^T : M=4096, K=2048, N=4096 (4 gates x 1024 units)
// Round 4: 256^2 8-phase GEMM (T1+T2+T3/T4+T5) with fused per-lane LSTM epilogue.
// W packed as rp = (u>>4)*64 + gate*16 + (u&15) so a wave's 4 n-frags = 4 gates of one unit.

typedef __attribute__((ext_vector_type(8))) short bf16x8;
typedef __attribute__((ext_vector_type(4))) float f32x4;
typedef __attribute__((ext_vector_type(8))) unsigned short u16x8;

__device__ __forceinline__ unsigned short f2bf(float f) {
  union { float f; uint32_t u; } v; v.f = f;
  uint32_t u = v.u;
  u += 0x7FFFu + ((u >> 16) & 1);   // RNE
  return (unsigned short)(u >> 16);
}
__device__ __forceinline__ float fast_sigmoid(float x) { return 1.f / (1.f + __expf(-x)); }
__device__ __forceinline__ float fast_tanh(float x) { return 1.f - 2.f / (1.f + __expf(2.f * x)); }

// ---------------- merged pack kernel: fp32 -> bf16 ----------------
// blocks 0..4095:    Ap[b][0:2048] = [x[b] | h[b]]
// blocks 4096..8191: Wp[rp][0:2048] = [Wx_g[u] | Wh_g[u]],  rp=(u>>4)*64+g*16+(u&15)
__global__ __launch_bounds__(256) void pack_kernel(
    const float* __restrict__ x, const float* __restrict__ hprev,
    const float* __restrict__ W_ii, const float* __restrict__ W_if,
    const float* __restrict__ W_ig, const float* __restrict__ W_io,
    const float* __restrict__ W_hi, const float* __restrict__ W_hf,
    const float* __restrict__ W_hg, const float* __restrict__ W_ho,
    unsigned short* __restrict__ Ap, unsigned short* __restrict__ Wp) {
  const int bid = blockIdx.x;
  const int k = threadIdx.x << 3;
  const float* src;
  unsigned short* dst;
  if (bid < 4096) {
    const int b = bid;
    src = (k < 1024) ? (x + (size_t)b * 1024 + k) : (hprev + (size_t)b * 1024 + (k - 1024));
    dst = Ap + (size_t)b * 2048 + k;
  } else {
    const int rp = bid - 4096;
    const int g = (rp >> 4) & 3;
    const int u = ((rp >> 6) << 4) | (rp & 15);
    const float* wx = (g == 0) ? W_ii : (g == 1) ? W_if : (g == 2) ? W_ig : W_io;
    const float* wh = (g == 0) ? W_hi : (g == 1) ? W_hf : (g == 2) ? W_hg : W_ho;
    src = (k < 1024) ? (wx + (size_t)u * 1024 + k) : (wh + (size_t)u * 1024 + (k - 1024));
    dst = Wp + (size_t)rp * 2048 + k;
  }
  float4 v0 = *(const float4*)src;
  float4 v1 = *(const float4*)(src + 4);
  u16x8 o;
  o[0] = f2bf(v0.x); o[1] = f2bf(v0.y); o[2] = f2bf(v0.z); o[3] = f2bf(v0.w);
  o[4] = f2bf(v1.x); o[5] = f2bf(v1.y); o[6] = f2bf(v1.z); o[7] = f2bf(v1.w);
  *(u16x8*)dst = o;
}

// ---------------- 256^2 8-phase GEMM + fused LSTM epilogue ----------------
// LDS: A region [0,64K): buf b at b*32768, half h at h*16384 (256 rows x 128B, st_16x32 swz)
//      B region [64K,128K): same layout. Swizzle: phys_byte = row*128 + (kb ^ (((row>>2)&1)<<5))

#define GL16(g, l)                                                                   \
  __builtin_amdgcn_global_load_lds(                                                  \
      (const __attribute__((address_space(1))) unsigned int*)(g),                    \
      (__attribute__((address_space(3))) unsigned int*)(l), 16, 0, 0)

// stage one half-tile (128 rows x 64 k) = 2 loads/thread; LDS dest linear,
// global source pre-inverse-swizzled (rule #21).
#define STAGE_A(BUF, H, KT)                                                          \
  { GL16(pA0 + (size_t)(H) * 524288 + (size_t)(KT) * 128,                            \
         lds + (BUF) * 32768 + (H) * 16384 + wvoff);                                 \
    GL16(pA1 + (size_t)(H) * 524288 + (size_t)(KT) * 128,                            \
         lds + (BUF) * 32768 + (H) * 16384 + 8192 + wvoff); }
#define STAGE_B(BUF, H, KT)                                                          \
  { GL16(pB0 + (size_t)(H) * 524288 + (size_t)(KT) * 128,                            \
         lds + 65536 + (BUF) * 32768 + (H) * 16384 + wvoff);                         \
    GL16(pB1 + (size_t)(H) * 524288 + (size_t)(KT) * 128,                            \
         lds + 65536 + (BUF) * 32768 + (H) * 16384 + 8192 + wvoff); }

#define DS_A(BUF, QQ)                                                                \
  { const char* Ab_ = lds + (BUF) * 32768 + tbA + (QQ) * 4096;                       \
    a00 = *(const bf16x8*)(Ab_);        a01 = *(const bf16x8*)(Ab_ + 64);            \
    a10 = *(const bf16x8*)(Ab_ + 2048); a11 = *(const bf16x8*)(Ab_ + 2048 + 64); }

#define DS_B(BUF)                                                                    \
  { const char* Bb_ = lds + 65536 + (BUF) * 32768 + tbB;                             \
    _Pragma("unroll")                                                                \
    for (int ni = 0; ni < 4; ++ni) {                                                 \
      breg[ni][0] = *(const bf16x8*)(Bb_ + ni * 2048);                               \
      breg[ni][1] = *(const bf16x8*)(Bb_ + ni * 2048 + 64);                          \
    } }

#define MFMA_CLUSTER(QQ)                                                             \
  { __builtin_amdgcn_s_setprio(1);                                                   \
    _Pragma("unroll")                                                                \
    for (int ni = 0; ni < 4; ++ni) {                                                 \
      acc[2*(QQ)][ni]   = __builtin_amdgcn_mfma_f32_16x16x32_bf16(a00, breg[ni][0], acc[2*(QQ)][ni], 0,0,0);   \
      acc[2*(QQ)][ni]   = __builtin_amdgcn_mfma_f32_16x16x32_bf16(a01, breg[ni][1], acc[2*(QQ)][ni], 0,0,0);   \
      acc[2*(QQ)+1][ni] = __builtin_amdgcn_mfma_f32_16x16x32_bf16(a10, breg[ni][0], acc[2*(QQ)+1][ni], 0,0,0); \
      acc[2*(QQ)+1][ni] = __builtin_amdgcn_mfma_f32_16x16x32_bf16(a11, breg[ni][1], acc[2*(QQ)+1][ni], 0,0,0); \
    }                                                                                \
    __builtin_amdgcn_s_setprio(0); }

#define BAR()      __builtin_amdgcn_s_barrier()
#define LGKM0()    asm volatile("s_waitcnt lgkmcnt(0)" ::: "memory")
#define LGKM8()    asm volatile("s_waitcnt lgkmcnt(8)" ::: "memory")
#define VMC4()     asm volatile("s_waitcnt vmcnt(4)" ::: "memory")

__global__ __launch_bounds__(512, 2) void lstm_gemm_kernel(
    const unsigned short* __restrict__ Ap, const unsigned short* __restrict__ Wp,
    const float* __restrict__ b_ii, const float* __restrict__ b_hi,
    const float* __restrict__ b_if, const float* __restrict__ b_hf,
    const float* __restrict__ b_ig, const float* __restrict__ b_hg,
    const float* __restrict__ b_io, const float* __restrict__ b_ho,
    const float* __restrict__ prev_c,
    float* __restrict__ out_h, float* __restrict__ out_c) {
  __shared__ char lds[131072];

  const int tid  = threadIdx.x;
  const int lane = tid & 63;
  const int wv   = tid >> 6;          // 0..7
  const int wm   = wv >> 2;           // 0..1 : M-half (128 rows)
  const int wn   = wv & 3;            // 0..3 : N-quarter (64 cols)

  // XCD-aware chunked swizzle (256 blocks, 8 XCDs -> bijective)
  const int bid = blockIdx.x;
  const int sid = (bid & 7) * 32 + (bid >> 3);
  const int bx  = sid & 15;           // M-tile (batch)
  const int by  = sid >> 4;           // N-tile (packed W rows)

  // ---- per-thread stage source pointers (inverse-swizzled global, rule #21) ----
  // idx_j = j*512 + tid ; r = idx>>3 in [0,128) ; kb = (idx&7)*16 ^ (((r>>2)&1)<<5)
  const int r0  = tid >> 3;                 // j=0
  const int r1  = (tid + 512) >> 3;         // j=1
  const int kb0 = ((tid & 7) << 4) ^ (((r0 >> 2) & 1) << 5);
  const int kb1 = ((tid & 7) << 4) ^ (((r1 >> 2) & 1) << 5);
  const char* ApC = (const char*)Ap;
  const char* BpC = (const char*)Wp;
  const char* pA0 = ApC + (size_t)(bx * 256 + r0) * 4096 + kb0;
  const char* pA1 = ApC + (size_t)(bx * 256 + r1) * 4096 + kb1;
  const char* pB0 = BpC + (size_t)(by * 256 + r0) * 4096 + kb0;
  const char* pB1 = BpC + (size_t)(by * 256 + r1) * 4096 + kb1;
  const int wvoff = wv * 1024;

  // ---- per-thread ds_read bases (swizzled read side) ----
  // frag row = base + (lane&15); k-byte = kk*64 + ((lane>>4) ^ (2*((lane>>2)&1)))*16
  const int qeff16 = (((lane >> 4) ^ (((lane >> 2) & 1) << 1)) << 4);
  const int tbA = (wm * 128 + (lane & 15)) * 128 + qeff16;
  const int tbB = (wn * 64 + (lane & 15)) * 128 + qeff16;

  f32x4 acc[8][4];
#pragma unroll
  for (int mi = 0; mi < 8; ++mi)
#pragma unroll
    for (int ni = 0; ni < 4; ++ni) acc[mi][ni] = (f32x4){0.f, 0.f, 0.f, 0.f};

  bf16x8 breg[4][2];
  bf16x8 a00, a01, a10, a11;

  // ---- prologue: stage tile0 (buf0 A+B) and tile1 B (buf1) ----
  STAGE_B(0, 0, 0); STAGE_B(0, 1, 0);
  STAGE_A(0, 0, 0); STAGE_A(0, 1, 0);
  STAGE_B(1, 0, 1); STAGE_B(1, 1, 1);
  VMC4();          // 12 loads issued; wait until 4 outstanding -> buf0 (8 loads) landed
  BAR();

  // ---- main loop: 16 iters x 2 K-tiles. Stage-safety proven per phase:
  // buf.B is read only in its K-tile's q0 phase; buf.A read through q3.
  // Every stage below is issued after the end-barrier of its target's last reader.
  for (int i = 0; i < 16; ++i) {
    const int T  = i << 1;
    const int k1 = (T + 1) & 31;
    const int k2 = (T + 2) & 31;
    const int k3 = (T + 3) & 31;

    // ph1: q0 buf0 | stage buf1.A.h0 (tile k1; buf1.A dead since prev ph8 barrier)
    DS_B(0); DS_A(0, 0);
    STAGE_A(1, 0, k1);
    LGKM8();
    BAR(); LGKM0();
    MFMA_CLUSTER(0);
    BAR();
    // ph2: q1 buf0 | stage buf1.A.h1
    DS_A(0, 1);
    STAGE_A(1, 1, k1);
    BAR(); LGKM0();
    MFMA_CLUSTER(1);
    BAR();
    // ph3: q2 buf0 | stage buf0.B.h0 (tile k2; buf0.B dead after ph1 barrier)
    DS_A(0, 2);
    STAGE_B(0, 0, k2);
    BAR(); LGKM0();
    MFMA_CLUSTER(2);
    BAR();
    // ph4: q3 buf0 | stage buf0.B.h1 ; vmcnt(4) -> ph1/ph2 stages (buf1.A) landed
    DS_A(0, 3);
    STAGE_B(0, 1, k2);
    VMC4();
    BAR(); LGKM0();
    MFMA_CLUSTER(3);
    BAR();
    // ph5: q0 buf1 | stage buf0.A.h0 (tile k2; buf0.A dead after ph4 barrier)
    DS_B(1); DS_A(1, 0);
    STAGE_A(0, 0, k2);
    LGKM8();
    BAR(); LGKM0();
    MFMA_CLUSTER(0);
    BAR();
    // ph6: q1 buf1 | stage buf0.A.h1
    DS_A(1, 1);
    STAGE_A(0, 1, k2);
    BAR(); LGKM0();
    MFMA_CLUSTER(1);
    BAR();
    // ph7: q2 buf1 | stage buf1.B.h0 (tile k3; buf1.B dead after ph5 barrier)
    DS_A(1, 2);
    STAGE_B(1, 0, k3);
    BAR(); LGKM0();
    MFMA_CLUSTER(2);
    BAR();
    // ph8: q3 buf1 | stage buf1.B.h1 ; vmcnt(4) -> ph5/ph6 stages (buf0.A) landed
    DS_A(1, 3);
    STAGE_B(1, 1, k3);
    VMC4();
    BAR(); LGKM0();
    MFMA_CLUSTER(3);
    BAR();
  }

  // ---- fused LSTM epilogue: lane's 4 n-frags = 4 gates of unit u ----
  const int u = ((by * 4 + wn) << 4) + (lane & 15);
  const float bsum0 = b_ii[u] + b_hi[u];
  const float bsum1 = b_if[u] + b_hf[u];
  const float bsum2 = b_ig[u] + b_hg[u];
  const float bsum3 = b_io[u] + b_ho[u];
  const int row0 = bx * 256 + wm * 128 + ((lane >> 4) << 2);

#pragma unroll
  for (int mi = 0; mi < 8; ++mi) {
#pragma unroll
    for (int rr = 0; rr < 4; ++rr) {
      const int row = row0 + mi * 16 + rr;
      const float gi = fast_sigmoid(acc[mi][0][rr] + bsum0);
      const float gf = fast_sigmoid(acc[mi][1][rr] + bsum1);
      const float gg = fast_tanh   (acc[mi][2][rr] + bsum2);
      const float go = fast_sigmoid(acc[mi][3][rr] + bsum3);
      const float cp = prev_c[(size_t)row * 1024 + u];
      const float c  = gf * cp + gi * gg;
      const float hh = go * fast_tanh(c);
      out_h[(size_t)row * 1024 + u] = hh;
      out_c[(size_t)row * 1024 + u] = c;
    }
  }
}

// ---------------- launch ----------------

extern "C" void kernel_launch(void* const* d_in, const int* in_sizes, int n_in,
                              void* d_out, int out_size, void* d_ws, size_t ws_size,
                              hipStream_t stream) {
  const float* input_ = (const float*)d_in[0];
  const float* prev_h = (const float*)d_in[1];
  const float* prev_c = (const float*)d_in[2];
  const float* W_ii = (const float*)d_in[3];  const float* b_ii = (const float*)d_in[4];
  const float* W_hi = (const float*)d_in[5];  const float* b_hi = (const float*)d_in[6];
  const float* W_if = (const float*)d_in[7];  const float* b_if = (const float*)d_in[8];
  const float* W_hf = (const float*)d_in[9];  const float* b_hf = (const float*)d_in[10];
  const float* W_ig = (const float*)d_in[11]; const float* b_ig = (const float*)d_in[12];
  const float* W_hg = (const float*)d_in[13]; const float* b_hg = (const float*)d_in[14];
  const float* W_io = (const float*)d_in[15]; const float* b_io = (const float*)d_in[16];
  const float* W_ho = (const float*)d_in[17]; const float* b_ho = (const float*)d_in[18];

  unsigned short* Ap = (unsigned short*)d_ws;                   // 4096x2048 bf16 = 16MB
  unsigned short* Wp = Ap + (size_t)4096 * 2048;                // 4096x2048 bf16 = 16MB

  pack_kernel<<<8192, 256, 0, stream>>>(input_, prev_h,
                                        W_ii, W_if, W_ig, W_io,
                                        W_hi, W_hf, W_hg, W_ho, Ap, Wp);

  float* out_h = (float*)d_out;
  float* out_c = out_h + (size_t)4096 * 1024;
  lstm_gemm_kernel<<<256, 512, 0, stream>>>(Ap, Wp,
                                            b_ii, b_hi, b_if, b_hf,
                                            b_ig, b_hg, b_io, b_ho,
                                            prev_c, out_h, out_c);
}

// Round 7
// 211.627 us; speedup vs baseline: 1.1906x; 1.0074x over previous
//
#include <hip/hip_runtime.h>
#include <hip/hip_bf16.h>
#include <stdint.h>

// LSTM cell: B=4096, IN=1024, H=1024.
// gates = [x|h] @ W^T : M=4096, K=2048, N=4096 (4 gates x 1024 units)
// Round 6: 256^2 8-phase GEMM; swizzle upgraded 1-bit -> 3-bit
// (slot bits [6:4] ^= row bits [3:1]) so 16-lane fragment reads are 2-way (free).
// W packed as rp = (u>>4)*64 + gate*16 + (u&15) so a wave's 4 n-frags = 4 gates of one unit.

typedef __attribute__((ext_vector_type(8))) short bf16x8;
typedef __attribute__((ext_vector_type(4))) float f32x4;
typedef __attribute__((ext_vector_type(8))) unsigned short u16x8;

__device__ __forceinline__ unsigned short f2bf(float f) {
  union { float f; uint32_t u; } v; v.f = f;
  uint32_t u = v.u;
  u += 0x7FFFu + ((u >> 16) & 1);   // RNE
  return (unsigned short)(u >> 16);
}
__device__ __forceinline__ float fast_sigmoid(float x) { return 1.f / (1.f + __expf(-x)); }
__device__ __forceinline__ float fast_tanh(float x) { return 1.f - 2.f / (1.f + __expf(2.f * x)); }

// ---------------- merged pack kernel: fp32 -> bf16 ----------------
// blocks 0..4095:    Ap[b][0:2048] = [x[b] | h[b]]
// blocks 4096..8191: Wp[rp][0:2048] = [Wx_g[u] | Wh_g[u]],  rp=(u>>4)*64+g*16+(u&15)
__global__ __launch_bounds__(256) void pack_kernel(
    const float* __restrict__ x, const float* __restrict__ hprev,
    const float* __restrict__ W_ii, const float* __restrict__ W_if,
    const float* __restrict__ W_ig, const float* __restrict__ W_io,
    const float* __restrict__ W_hi, const float* __restrict__ W_hf,
    const float* __restrict__ W_hg, const float* __restrict__ W_ho,
    unsigned short* __restrict__ Ap, unsigned short* __restrict__ Wp) {
  const int bid = blockIdx.x;
  const int k = threadIdx.x << 3;
  const float* src;
  unsigned short* dst;
  if (bid < 4096) {
    const int b = bid;
    src = (k < 1024) ? (x + (size_t)b * 1024 + k) : (hprev + (size_t)b * 1024 + (k - 1024));
    dst = Ap + (size_t)b * 2048 + k;
  } else {
    const int rp = bid - 4096;
    const int g = (rp >> 4) & 3;
    const int u = ((rp >> 6) << 4) | (rp & 15);
    const float* wx = (g == 0) ? W_ii : (g == 1) ? W_if : (g == 2) ? W_ig : W_io;
    const float* wh = (g == 0) ? W_hi : (g == 1) ? W_hf : (g == 2) ? W_hg : W_ho;
    src = (k < 1024) ? (wx + (size_t)u * 1024 + k) : (wh + (size_t)u * 1024 + (k - 1024));
    dst = Wp + (size_t)rp * 2048 + k;
  }
  float4 v0 = *(const float4*)src;
  float4 v1 = *(const float4*)(src + 4);
  u16x8 o;
  o[0] = f2bf(v0.x); o[1] = f2bf(v0.y); o[2] = f2bf(v0.z); o[3] = f2bf(v0.w);
  o[4] = f2bf(v1.x); o[5] = f2bf(v1.y); o[6] = f2bf(v1.z); o[7] = f2bf(v1.w);
  *(u16x8*)dst = o;
}

// ---------------- 256^2 8-phase GEMM + fused LSTM epilogue ----------------
// LDS: A region [0,64K): buf b at b*32768, half h at h*16384 (128 rows x 128B).
//      B region [64K,128K): same layout.
// Swizzle (3-bit): logical (row, kb) lives at phys byte row*128 + (kb ^ (((row>>1)&7)<<4)).
// Read fragments: 16 consecutive rows at one 16B slot -> slots spread over all 8 -> 2-way (free).

#define GL16(g, l)                                                                   \
  __builtin_amdgcn_global_load_lds(                                                  \
      (const __attribute__((address_space(1))) unsigned int*)(g),                    \
      (__attribute__((address_space(3))) unsigned int*)(l), 16, 0, 0)

// stage one half-tile (128 rows x 64 k) = 2 loads/thread; LDS dest linear,
// global source pre-inverse-swizzled (rule #21: both sides, same involution).
#define STAGE_A(BUF, H, KT)                                                          \
  { GL16(pA0 + (size_t)(H) * 524288 + (size_t)(KT) * 128,                            \
         lds + (BUF) * 32768 + (H) * 16384 + wvoff);                                 \
    GL16(pA1 + (size_t)(H) * 524288 + (size_t)(KT) * 128,                            \
         lds + (BUF) * 32768 + (H) * 16384 + 8192 + wvoff); }
#define STAGE_B(BUF, H, KT)                                                          \
  { GL16(pB0 + (size_t)(H) * 524288 + (size_t)(KT) * 128,                            \
         lds + 65536 + (BUF) * 32768 + (H) * 16384 + wvoff);                         \
    GL16(pB1 + (size_t)(H) * 524288 + (size_t)(KT) * 128,                            \
         lds + 65536 + (BUF) * 32768 + (H) * 16384 + 8192 + wvoff); }

// second k-half (logical +64 bytes) is base XOR 64 under the 3-bit swizzle -> off0/off1.
#define DS_A(BUF, QQ)                                                                \
  { const char* Ab_ = lds + (BUF) * 32768 + tbA + (QQ) * 4096;                       \
    a00 = *(const bf16x8*)(Ab_ + off0);        a01 = *(const bf16x8*)(Ab_ + off1);   \
    a10 = *(const bf16x8*)(Ab_ + 2048 + off0); a11 = *(const bf16x8*)(Ab_ + 2048 + off1); }

#define DS_B(BUF)                                                                    \
  { const char* Bb_ = lds + 65536 + (BUF) * 32768 + tbB;                             \
    _Pragma("unroll")                                                                \
    for (int ni = 0; ni < 4; ++ni) {                                                 \
      breg[ni][0] = *(const bf16x8*)(Bb_ + ni * 2048 + off0);                        \
      breg[ni][1] = *(const bf16x8*)(Bb_ + ni * 2048 + off1);                        \
    } }

#define MFMA_CLUSTER(QQ)                                                             \
  { __builtin_amdgcn_s_setprio(1);                                                   \
    _Pragma("unroll")                                                                \
    for (int ni = 0; ni < 4; ++ni) {                                                 \
      acc[2*(QQ)][ni]   = __builtin_amdgcn_mfma_f32_16x16x32_bf16(a00, breg[ni][0], acc[2*(QQ)][ni], 0,0,0);   \
      acc[2*(QQ)][ni]   = __builtin_amdgcn_mfma_f32_16x16x32_bf16(a01, breg[ni][1], acc[2*(QQ)][ni], 0,0,0);   \
      acc[2*(QQ)+1][ni] = __builtin_amdgcn_mfma_f32_16x16x32_bf16(a10, breg[ni][0], acc[2*(QQ)+1][ni], 0,0,0); \
      acc[2*(QQ)+1][ni] = __builtin_amdgcn_mfma_f32_16x16x32_bf16(a11, breg[ni][1], acc[2*(QQ)+1][ni], 0,0,0); \
    }                                                                                \
    __builtin_amdgcn_s_setprio(0); }

#define BAR()      __builtin_amdgcn_s_barrier()
#define LGKM0()    asm volatile("s_waitcnt lgkmcnt(0)" ::: "memory")
#define LGKM8()    asm volatile("s_waitcnt lgkmcnt(8)" ::: "memory")
#define VMC4()     asm volatile("s_waitcnt vmcnt(4)" ::: "memory")

__global__ __launch_bounds__(512, 2) void lstm_gemm_kernel(
    const unsigned short* __restrict__ Ap, const unsigned short* __restrict__ Wp,
    const float* __restrict__ b_ii, const float* __restrict__ b_hi,
    const float* __restrict__ b_if, const float* __restrict__ b_hf,
    const float* __restrict__ b_ig, const float* __restrict__ b_hg,
    const float* __restrict__ b_io, const float* __restrict__ b_ho,
    const float* __restrict__ prev_c,
    float* __restrict__ out_h, float* __restrict__ out_c) {
  __shared__ char lds[131072];

  const int tid  = threadIdx.x;
  const int lane = tid & 63;
  const int wv   = tid >> 6;          // 0..7
  const int wm   = wv >> 2;           // 0..1 : M-half (128 rows)
  const int wn   = wv & 3;            // 0..3 : N-quarter (64 cols)

  // XCD-aware chunked swizzle (256 blocks, 8 XCDs -> bijective)
  const int bid = blockIdx.x;
  const int sid = (bid & 7) * 32 + (bid >> 3);
  const int bx  = sid & 15;           // M-tile (batch)
  const int by  = sid >> 4;           // N-tile (packed W rows)

  // ---- per-thread stage source pointers (inverse-swizzled global) ----
  // thread covers LDS slot s=(tid&7) of row r; content there = logical kb = (s ^ ((r>>1)&7))<<4
  const int r0  = tid >> 3;                 // j=0 rows 0..63
  const int r1  = (tid + 512) >> 3;         // j=1 rows 64..127
  const int kb0 = (((tid & 7) ^ ((r0 >> 1) & 7)) << 4);
  const int kb1 = (((tid & 7) ^ ((r1 >> 1) & 7)) << 4);
  const char* ApC = (const char*)Ap;
  const char* BpC = (const char*)Wp;
  const char* pA0 = ApC + (size_t)(bx * 256 + r0) * 4096 + kb0;
  const char* pA1 = ApC + (size_t)(bx * 256 + r1) * 4096 + kb1;
  const char* pB0 = BpC + (size_t)(by * 256 + r0) * 4096 + kb0;
  const char* pB1 = BpC + (size_t)(by * 256 + r1) * 4096 + kb1;
  const int wvoff = wv * 1024;

  // ---- per-thread ds_read bases (swizzled read side) ----
  // fragment row = base + (lane&15) (base mult of 16) -> row bits[3:1] = lane bits[3:1]
  const int qe   = (lane >> 4) ^ ((lane >> 1) & 7);
  const int off0 = qe << 4;            // k-half 0 slot
  const int off1 = (qe ^ 4) << 4;      // k-half 1 (logical +64B) slot
  const int tbA = (wm * 128 + (lane & 15)) * 128;
  const int tbB = (wn * 64 + (lane & 15)) * 128;

  f32x4 acc[8][4];
#pragma unroll
  for (int mi = 0; mi < 8; ++mi)
#pragma unroll
    for (int ni = 0; ni < 4; ++ni) acc[mi][ni] = (f32x4){0.f, 0.f, 0.f, 0.f};

  bf16x8 breg[4][2];
  bf16x8 a00, a01, a10, a11;

  // ---- prologue: stage tile0 (buf0 A+B) and tile1 B (buf1) ----
  STAGE_B(0, 0, 0); STAGE_B(0, 1, 0);
  STAGE_A(0, 0, 0); STAGE_A(0, 1, 0);
  STAGE_B(1, 0, 1); STAGE_B(1, 1, 1);
  VMC4();          // 12 loads issued; wait until 4 outstanding -> buf0 (8 loads) landed
  BAR();

  // ---- main loop: 16 iters x 2 K-tiles. Stage-safety per phase:
  // buf.B read only in its K-tile's q0 phase; buf.A read through q3.
  // Every stage is issued after the end-barrier of its target's last reader.
  for (int i = 0; i < 16; ++i) {
    const int T  = i << 1;
    const int k1 = (T + 1) & 31;
    const int k2 = (T + 2) & 31;
    const int k3 = (T + 3) & 31;

    // ph1: q0 buf0 | stage buf1.A.h0 (tile k1)
    DS_B(0); DS_A(0, 0);
    STAGE_A(1, 0, k1);
    LGKM8();
    BAR(); LGKM0();
    MFMA_CLUSTER(0);
    BAR();
    // ph2: q1 buf0 | stage buf1.A.h1
    DS_A(0, 1);
    STAGE_A(1, 1, k1);
    BAR(); LGKM0();
    MFMA_CLUSTER(1);
    BAR();
    // ph3: q2 buf0 | stage buf0.B.h0 (tile k2)
    DS_A(0, 2);
    STAGE_B(0, 0, k2);
    BAR(); LGKM0();
    MFMA_CLUSTER(2);
    BAR();
    // ph4: q3 buf0 | stage buf0.B.h1 ; vmcnt(4) -> ph1/ph2 stages (buf1.A) landed
    DS_A(0, 3);
    STAGE_B(0, 1, k2);
    VMC4();
    BAR(); LGKM0();
    MFMA_CLUSTER(3);
    BAR();
    // ph5: q0 buf1 | stage buf0.A.h0 (tile k2)
    DS_B(1); DS_A(1, 0);
    STAGE_A(0, 0, k2);
    LGKM8();
    BAR(); LGKM0();
    MFMA_CLUSTER(0);
    BAR();
    // ph6: q1 buf1 | stage buf0.A.h1
    DS_A(1, 1);
    STAGE_A(0, 1, k2);
    BAR(); LGKM0();
    MFMA_CLUSTER(1);
    BAR();
    // ph7: q2 buf1 | stage buf1.B.h0 (tile k3)
    DS_A(1, 2);
    STAGE_B(1, 0, k3);
    BAR(); LGKM0();
    MFMA_CLUSTER(2);
    BAR();
    // ph8: q3 buf1 | stage buf1.B.h1 ; vmcnt(4) -> ph5/ph6 stages (buf0.A) landed
    DS_A(1, 3);
    STAGE_B(1, 1, k3);
    VMC4();
    BAR(); LGKM0();
    MFMA_CLUSTER(3);
    BAR();
  }

  // ---- fused LSTM epilogue: lane's 4 n-frags = 4 gates of unit u ----
  const int u = ((by * 4 + wn) << 4) + (lane & 15);
  const float bsum0 = b_ii[u] + b_hi[u];
  const float bsum1 = b_if[u] + b_hf[u];
  const float bsum2 = b_ig[u] + b_hg[u];
  const float bsum3 = b_io[u] + b_ho[u];
  const int row0 = bx * 256 + wm * 128 + ((lane >> 4) << 2);

#pragma unroll
  for (int mi = 0; mi < 8; ++mi) {
#pragma unroll
    for (int rr = 0; rr < 4; ++rr) {
      const int row = row0 + mi * 16 + rr;
      const float gi = fast_sigmoid(acc[mi][0][rr] + bsum0);
      const float gf = fast_sigmoid(acc[mi][1][rr] + bsum1);
      const float gg = fast_tanh   (acc[mi][2][rr] + bsum2);
      const float go = fast_sigmoid(acc[mi][3][rr] + bsum3);
      const float cp = prev_c[(size_t)row * 1024 + u];
      const float c  = gf * cp + gi * gg;
      const float hh = go * fast_tanh(c);
      out_h[(size_t)row * 1024 + u] = hh;
      out_c[(size_t)row * 1024 + u] = c;
    }
  }
}

// ---------------- launch ----------------

extern "C" void kernel_launch(void* const* d_in, const int* in_sizes, int n_in,
                              void* d_out, int out_size, void* d_ws, size_t ws_size,
                              hipStream_t stream) {
  const float* input_ = (const float*)d_in[0];
  const float* prev_h = (const float*)d_in[1];
  const float* prev_c = (const float*)d_in[2];
  const float* W_ii = (const float*)d_in[3];  const float* b_ii = (const float*)d_in[4];
  const float* W_hi = (const float*)d_in[5];  const float* b_hi = (const float*)d_in[6];
  const float* W_if = (const float*)d_in[7];  const float* b_if = (const float*)d_in[8];
  const float* W_hf = (const float*)d_in[9];  const float* b_hf = (const float*)d_in[10];
  const float* W_ig = (const float*)d_in[11]; const float* b_ig = (const float*)d_in[12];
  const float* W_hg = (const float*)d_in[13]; const float* b_hg = (const float*)d_in[14];
  const float* W_io = (const float*)d_in[15]; const float* b_io = (const float*)d_in[16];
  const float* W_ho = (const float*)d_in[17]; const float* b_ho = (const float*)d_in[18];

  unsigned short* Ap = (unsigned short*)d_ws;                   // 4096x2048 bf16 = 16MB
  unsigned short* Wp = Ap + (size_t)4096 * 2048;                // 4096x2048 bf16 = 16MB

  pack_kernel<<<8192, 256, 0, stream>>>(input_, prev_h,
                                        W_ii, W_if, W_ig, W_io,
                                        W_hi, W_hf, W_hg, W_ho, Ap, Wp);

  float* out_h = (float*)d_out;
  float* out_c = out_h + (size_t)4096 * 1024;
  lstm_gemm_kernel<<<256, 512, 0, stream>>>(Ap, Wp,
                                            b_ii, b_hi, b_if, b_hf,
                                            b_ig, b_hg, b_io, b_ho,
                                            prev_c, out_h, out_c);
}

// Round 11
// 209.638 us; speedup vs baseline: 1.2019x; 1.0095x over previous
//
#include <hip/hip_runtime.h>
#include <hip/hip_bf16.h>
#include <stdint.h>

// LSTM cell: B=4096, IN=1024, H=1024.
// gates = [x|h] @ W^T : M=4096, K=2048, N=4096 (4 gates x 1024 units)
// Round 8: 256^2 8-phase GEMM + 3-bit swizzle (0 conflicts, R7) + NEW:
// register-level software pipeline — each phase's ds_reads issued one phase
// early into a second reg set, so LDS drain overlaps the previous MFMA burst.
// Barrier/vmcnt/STAGE schedule is byte-identical to the proven R7 kernel.

typedef __attribute__((ext_vector_type(8))) short bf16x8;
typedef __attribute__((ext_vector_type(4))) float f32x4;
typedef __attribute__((ext_vector_type(8))) unsigned short u16x8;

__device__ __forceinline__ unsigned short f2bf(float f) {
  union { float f; uint32_t u; } v; v.f = f;
  uint32_t u = v.u;
  u += 0x7FFFu + ((u >> 16) & 1);   // RNE
  return (unsigned short)(u >> 16);
}
__device__ __forceinline__ float fast_sigmoid(float x) { return 1.f / (1.f + __expf(-x)); }
__device__ __forceinline__ float fast_tanh(float x) { return 1.f - 2.f / (1.f + __expf(2.f * x)); }

// ---------------- merged pack kernel: fp32 -> bf16 ----------------
__global__ __launch_bounds__(256) void pack_kernel(
    const float* __restrict__ x, const float* __restrict__ hprev,
    const float* __restrict__ W_ii, const float* __restrict__ W_if,
    const float* __restrict__ W_ig, const float* __restrict__ W_io,
    const float* __restrict__ W_hi, const float* __restrict__ W_hf,
    const float* __restrict__ W_hg, const float* __restrict__ W_ho,
    unsigned short* __restrict__ Ap, unsigned short* __restrict__ Wp) {
  const int bid = blockIdx.x;
  const int k = threadIdx.x << 3;
  const float* src;
  unsigned short* dst;
  if (bid < 4096) {
    const int b = bid;
    src = (k < 1024) ? (x + (size_t)b * 1024 + k) : (hprev + (size_t)b * 1024 + (k - 1024));
    dst = Ap + (size_t)b * 2048 + k;
  } else {
    const int rp = bid - 4096;
    const int g = (rp >> 4) & 3;
    const int u = ((rp >> 6) << 4) | (rp & 15);
    const float* wx = (g == 0) ? W_ii : (g == 1) ? W_if : (g == 2) ? W_ig : W_io;
    const float* wh = (g == 0) ? W_hi : (g == 1) ? W_hf : (g == 2) ? W_hg : W_ho;
    src = (k < 1024) ? (wx + (size_t)u * 1024 + k) : (wh + (size_t)u * 1024 + (k - 1024));
    dst = Wp + (size_t)rp * 2048 + k;
  }
  float4 v0 = *(const float4*)src;
  float4 v1 = *(const float4*)(src + 4);
  u16x8 o;
  o[0] = f2bf(v0.x); o[1] = f2bf(v0.y); o[2] = f2bf(v0.z); o[3] = f2bf(v0.w);
  o[4] = f2bf(v1.x); o[5] = f2bf(v1.y); o[6] = f2bf(v1.z); o[7] = f2bf(v1.w);
  *(u16x8*)dst = o;
}

// ---------------- 256^2 8-phase GEMM + fused LSTM epilogue ----------------
// LDS: A [0,64K): buf b at b*32768, half h at h*16384 (128 rows x 128B).
//      B [64K,128K): same. Swizzle (3-bit): phys = row*128 + (kb ^ (((row>>1)&7)<<4)).

#define GL16(g, l)                                                                   \
  __builtin_amdgcn_global_load_lds(                                                  \
      (const __attribute__((address_space(1))) unsigned int*)(g),                    \
      (__attribute__((address_space(3))) unsigned int*)(l), 16, 0, 0)

#define STAGE_A(BUF, H, KT)                                                          \
  { GL16(pA0 + (size_t)(H) * 524288 + (size_t)(KT) * 128,                            \
         lds + (BUF) * 32768 + (H) * 16384 + wvoff);                                 \
    GL16(pA1 + (size_t)(H) * 524288 + (size_t)(KT) * 128,                            \
         lds + (BUF) * 32768 + (H) * 16384 + 8192 + wvoff); }
#define STAGE_B(BUF, H, KT)                                                          \
  { GL16(pB0 + (size_t)(H) * 524288 + (size_t)(KT) * 128,                            \
         lds + 65536 + (BUF) * 32768 + (H) * 16384 + wvoff);                         \
    GL16(pB1 + (size_t)(H) * 524288 + (size_t)(KT) * 128,                            \
         lds + 65536 + (BUF) * 32768 + (H) * 16384 + 8192 + wvoff); }

// load A quadrant QQ of buffer BUF into 4 named frags
#define DS_A_INTO(A0f, A1f, A2f, A3f, BUF, QQ)                                       \
  { const char* Ab_ = lds + (BUF) * 32768 + tbA + (QQ) * 4096;                       \
    A0f = *(const bf16x8*)(Ab_ + off0);        A1f = *(const bf16x8*)(Ab_ + off1);   \
    A2f = *(const bf16x8*)(Ab_ + 2048 + off0); A3f = *(const bf16x8*)(Ab_ + 2048 + off1); }

// load all 8 B frags of buffer BUF into named array
#define DS_B_INTO(BR, BUF)                                                           \
  { const char* Bb_ = lds + 65536 + (BUF) * 32768 + tbB;                             \
    _Pragma("unroll")                                                                \
    for (int ni = 0; ni < 4; ++ni) {                                                 \
      BR[ni][0] = *(const bf16x8*)(Bb_ + ni * 2048 + off0);                          \
      BR[ni][1] = *(const bf16x8*)(Bb_ + ni * 2048 + off1);                          \
    } }

#define MFMA_C(QQ, A0f, A1f, A2f, A3f, BR)                                           \
  { __builtin_amdgcn_s_setprio(1);                                                   \
    _Pragma("unroll")                                                                \
    for (int ni = 0; ni < 4; ++ni) {                                                 \
      acc[2*(QQ)][ni]   = __builtin_amdgcn_mfma_f32_16x16x32_bf16(A0f, BR[ni][0], acc[2*(QQ)][ni], 0,0,0);   \
      acc[2*(QQ)][ni]   = __builtin_amdgcn_mfma_f32_16x16x32_bf16(A1f, BR[ni][1], acc[2*(QQ)][ni], 0,0,0);   \
      acc[2*(QQ)+1][ni] = __builtin_amdgcn_mfma_f32_16x16x32_bf16(A2f, BR[ni][0], acc[2*(QQ)+1][ni], 0,0,0); \
      acc[2*(QQ)+1][ni] = __builtin_amdgcn_mfma_f32_16x16x32_bf16(A3f, BR[ni][1], acc[2*(QQ)+1][ni], 0,0,0); \
    }                                                                                \
    __builtin_amdgcn_s_setprio(0); }

#define BAR()      __builtin_amdgcn_s_barrier()
#define VMC4()     asm volatile("s_waitcnt vmcnt(4)" ::: "memory")

__global__ __launch_bounds__(512, 2) void lstm_gemm_kernel(
    const unsigned short* __restrict__ Ap, const unsigned short* __restrict__ Wp,
    const float* __restrict__ b_ii, const float* __restrict__ b_hi,
    const float* __restrict__ b_if, const float* __restrict__ b_hf,
    const float* __restrict__ b_ig, const float* __restrict__ b_hg,
    const float* __restrict__ b_io, const float* __restrict__ b_ho,
    const float* __restrict__ prev_c,
    float* __restrict__ out_h, float* __restrict__ out_c) {
  __shared__ char lds[131072];

  const int tid  = threadIdx.x;
  const int lane = tid & 63;
  const int wv   = tid >> 6;          // 0..7
  const int wm   = wv >> 2;           // 0..1 : M-half (128 rows)
  const int wn   = wv & 3;            // 0..3 : N-quarter (64 cols)

  // XCD-aware chunked swizzle (256 blocks, 8 XCDs -> bijective)
  const int bid = blockIdx.x;
  const int sid = (bid & 7) * 32 + (bid >> 3);
  const int bx  = sid & 15;           // M-tile (batch)
  const int by  = sid >> 4;           // N-tile (packed W rows)

  // ---- stage source pointers (inverse-swizzled global) ----
  const int r0  = tid >> 3;
  const int r1  = (tid + 512) >> 3;
  const int kb0 = (((tid & 7) ^ ((r0 >> 1) & 7)) << 4);
  const int kb1 = (((tid & 7) ^ ((r1 >> 1) & 7)) << 4);
  const char* ApC = (const char*)Ap;
  const char* BpC = (const char*)Wp;
  const char* pA0 = ApC + (size_t)(bx * 256 + r0) * 4096 + kb0;
  const char* pA1 = ApC + (size_t)(bx * 256 + r1) * 4096 + kb1;
  const char* pB0 = BpC + (size_t)(by * 256 + r0) * 4096 + kb0;
  const char* pB1 = BpC + (size_t)(by * 256 + r1) * 4096 + kb1;
  const int wvoff = wv * 1024;

  // ---- ds_read bases (swizzled read side) ----
  const int qe   = (lane >> 4) ^ ((lane >> 1) & 7);
  const int off0 = qe << 4;
  const int off1 = (qe ^ 4) << 4;
  const int tbA = (wm * 128 + (lane & 15)) * 128;
  const int tbB = (wn * 64 + (lane & 15)) * 128;

  f32x4 acc[8][4];
#pragma unroll
  for (int mi = 0; mi < 8; ++mi)
#pragma unroll
    for (int ni = 0; ni < 4; ++ni) acc[mi][ni] = (f32x4){0.f, 0.f, 0.f, 0.f};

  // double register sets: A alternates X/Y per phase; B per tile (bA=even buf, bB=odd buf)
  bf16x8 bA[4][2], bB[4][2];
  bf16x8 aX0, aX1, aX2, aX3, aY0, aY1, aY2, aY3;

  // ---- prologue: stage tile0 (buf0 A+B) and tile1 B (buf1); preload tile0 q0 frags ----
  STAGE_B(0, 0, 0); STAGE_B(0, 1, 0);
  STAGE_A(0, 0, 0); STAGE_A(0, 1, 0);
  STAGE_B(1, 0, 1); STAGE_B(1, 1, 1);
  VMC4();          // buf0 (8 oldest loads) resident
  BAR();
  DS_B_INTO(bA, 0);
  DS_A_INTO(aX0, aX1, aX2, aX3, 0, 0);

  // ---- main loop: STAGE/VMC4/BAR schedule identical to proven R7 kernel;
  // fragment reads moved one phase early (reg pipeline). Compiler inserts the
  // per-use lgkmcnt waits, so MFMA(CUR) never waits on NXT's in-flight reads.
  for (int i = 0; i < 16; ++i) {
    const int T  = i << 1;
    const int k1 = (T + 1) & 31;
    const int k2 = (T + 2) & 31;
    const int k3 = (T + 3) & 31;

    // ph1: MFMA q0 buf0 (aX,bA) | prefetch aY<-buf0.q1 | stage buf1.A.h0 (k1)
    STAGE_A(1, 0, k1);
    BAR();
    DS_A_INTO(aY0, aY1, aY2, aY3, 0, 1);
    MFMA_C(0, aX0, aX1, aX2, aX3, bA);
    BAR();
    // ph2: q1 (aY) | prefetch aX<-buf0.q2 | stage buf1.A.h1
    STAGE_A(1, 1, k1);
    BAR();
    DS_A_INTO(aX0, aX1, aX2, aX3, 0, 2);
    MFMA_C(1, aY0, aY1, aY2, aY3, bA);
    BAR();
    // ph3: q2 (aX) | prefetch aY<-buf0.q3 | stage buf0.B.h0 (k2)
    STAGE_B(0, 0, k2);
    BAR();
    DS_A_INTO(aY0, aY1, aY2, aY3, 0, 3);
    MFMA_C(2, aX0, aX1, aX2, aX3, bA);
    BAR();
    // ph4: q3 (aY) | prefetch bB<-buf1.B + aX<-buf1.q0 | stage buf0.B.h1 ; VMC4 gates buf1
    STAGE_B(0, 1, k2);
    VMC4();
    BAR();
    DS_B_INTO(bB, 1);
    DS_A_INTO(aX0, aX1, aX2, aX3, 1, 0);
    MFMA_C(3, aY0, aY1, aY2, aY3, bA);
    BAR();
    // ph5: q0 buf1 (aX,bB) | prefetch aY<-buf1.q1 | stage buf0.A.h0 (k2)
    STAGE_A(0, 0, k2);
    BAR();
    DS_A_INTO(aY0, aY1, aY2, aY3, 1, 1);
    MFMA_C(0, aX0, aX1, aX2, aX3, bB);
    BAR();
    // ph6: q1 (aY) | prefetch aX<-buf1.q2 | stage buf0.A.h1
    STAGE_A(0, 1, k2);
    BAR();
    DS_A_INTO(aX0, aX1, aX2, aX3, 1, 2);
    MFMA_C(1, aY0, aY1, aY2, aY3, bB);
    BAR();
    // ph7: q2 (aX) | prefetch aY<-buf1.q3 | stage buf1.B.h0 (k3)
    STAGE_B(1, 0, k3);
    BAR();
    DS_A_INTO(aY0, aY1, aY2, aY3, 1, 3);
    MFMA_C(2, aX0, aX1, aX2, aX3, bB);
    BAR();
    // ph8: q3 (aY) | prefetch bA<-buf0.B + aX<-buf0.q0 (next tile) | stage buf1.B.h1 ; VMC4 gates buf0
    STAGE_B(1, 1, k3);
    VMC4();
    BAR();
    DS_B_INTO(bA, 0);
    DS_A_INTO(aX0, aX1, aX2, aX3, 0, 0);
    MFMA_C(3, aY0, aY1, aY2, aY3, bB);
    BAR();
  }

  // ---- fused LSTM epilogue: lane's 4 n-frags = 4 gates of unit u ----
  const int u = ((by * 4 + wn) << 4) + (lane & 15);
  const float bsum0 = b_ii[u] + b_hi[u];
  const float bsum1 = b_if[u] + b_hf[u];
  const float bsum2 = b_ig[u] + b_hg[u];
  const float bsum3 = b_io[u] + b_ho[u];
  const int row0 = bx * 256 + wm * 128 + ((lane >> 4) << 2);

#pragma unroll
  for (int mi = 0; mi < 8; ++mi) {
#pragma unroll
    for (int rr = 0; rr < 4; ++rr) {
      const int row = row0 + mi * 16 + rr;
      const float gi = fast_sigmoid(acc[mi][0][rr] + bsum0);
      const float gf = fast_sigmoid(acc[mi][1][rr] + bsum1);
      const float gg = fast_tanh   (acc[mi][2][rr] + bsum2);
      const float go = fast_sigmoid(acc[mi][3][rr] + bsum3);
      const float cp = prev_c[(size_t)row * 1024 + u];
      const float c  = gf * cp + gi * gg;
      const float hh = go * fast_tanh(c);
      out_h[(size_t)row * 1024 + u] = hh;
      out_c[(size_t)row * 1024 + u] = c;
    }
  }
}

// ---------------- launch ----------------

extern "C" void kernel_launch(void* const* d_in, const int* in_sizes, int n_in,
                              void* d_out, int out_size, void* d_ws, size_t ws_size,
                              hipStream_t stream) {
  const float* input_ = (const float*)d_in[0];
  const float* prev_h = (const float*)d_in[1];
  const float* prev_c = (const float*)d_in[2];
  const float* W_ii = (const float*)d_in[3];  const float* b_ii = (const float*)d_in[4];
  const float* W_hi = (const float*)d_in[5];  const float* b_hi = (const float*)d_in[6];
  const float* W_if = (const float*)d_in[7];  const float* b_if = (const float*)d_in[8];
  const float* W_hf = (const float*)d_in[9];  const float* b_hf = (const float*)d_in[10];
  const float* W_ig = (const float*)d_in[11]; const float* b_ig = (const float*)d_in[12];
  const float* W_hg = (const float*)d_in[13]; const float* b_hg = (const float*)d_in[14];
  const float* W_io = (const float*)d_in[15]; const float* b_io = (const float*)d_in[16];
  const float* W_ho = (const float*)d_in[17]; const float* b_ho = (const float*)d_in[18];

  unsigned short* Ap = (unsigned short*)d_ws;                   // 4096x2048 bf16 = 16MB
  unsigned short* Wp = Ap + (size_t)4096 * 2048;                // 4096x2048 bf16 = 16MB

  pack_kernel<<<8192, 256, 0, stream>>>(input_, prev_h,
                                        W_ii, W_if, W_ig, W_io,
                                        W_hi, W_hf, W_hg, W_ho, Ap, Wp);

  float* out_h = (float*)d_out;
  float* out_c = out_h + (size_t)4096 * 1024;
  lstm_gemm_kernel<<<256, 512, 0, stream>>>(Ap, Wp,
                                            b_ii, b_hi, b_if, b_hf,
                                            b_ig, b_hg, b_io, b_ho,
                                            prev_c, out_h, out_c);
}